// Round 13
// baseline (172.343 us; speedup 1.0000x reference)
//
#include <hip/hip_runtime.h>
#include <cstdint>

typedef _Float16 f16;
typedef _Float16 f16x4 __attribute__((ext_vector_type(4)));
typedef _Float16 f16x8 __attribute__((ext_vector_type(8)));
typedef float f32x4 __attribute__((ext_vector_type(4)));

#define MFMA16(a, b, c) __builtin_amdgcn_mfma_f32_16x16x32_f16(a, b, c, 0, 0, 0)
#define QSCALE 0.1803368801111243f  /* 0.125 * log2(e): scores land in log2 domain */

// direct global->LDS 16B async copy (m97 pattern)
__device__ __forceinline__ void gload_lds16(const void* g, void* l) {
    __builtin_amdgcn_global_load_lds((__attribute__((address_space(1))) void*)(g),
                                     (__attribute__((address_space(3))) void*)(l),
                                     16, 0, 0);
}

// Problem constants: S=2048, B=2, D=1024, H=16, DK=64
// ws layout (bytes):
//  xh   @ 0         : 4096x1024 f16 = 8 MB       (dead after gemm_qkv)
//  wqh  @ 8388608   : 3072x1024 f16 = 6 MB
//  woh  @ 14680064  : 1024x1024 f16 = 2 MB
//  qh   @ 16777216  : [32][2048][64] f16 = 8 MB  (PRE-SCALED by 0.125*log2e)
//  kh   @ 25165824  : [32][2048][64] f16 = 8 MB
//  vt   @ 33554432  : [32][64][2048] f16 = 8 MB  (V transposed, written by gemm_qkv)
//  ah   @ 41943040  : [4096][1024] f16 = 8 MB

// Single fused cast: outputs are contiguous in ws (xh | wqh | woh).
__global__ void cast_all(const float* __restrict__ x, const float* __restrict__ wqv,
                         const float* __restrict__ wo, f16* __restrict__ out) {
    int i = blockIdx.x * blockDim.x + threadIdx.x;  // 0..2097151 float4s
    const float* src; int li;
    if (i < 1048576)      { src = x;   li = i; }
    else if (i < 1835008) { src = wqv; li = i - 1048576; }
    else                  { src = wo;  li = i - 1835008; }
    float4 v = reinterpret_cast<const float4*>(src)[li];
    f16x4 o = {(f16)v.x, (f16)v.y, (f16)v.z, (f16)v.w};
    reinterpret_cast<f16x4*>(out)[i] = o;
}

// ---------------- QKV GEMM: C[4096x3072] = X[4096x1024] * Wqkv^T ----------------
// R18: R17's lever applied to the GEMM. Evidence: 32 barrier-iterations at ~3400cyc
// vs ~1.5k cyc resource floor -> ~1.9k cyc/iter fixed overhead. TWO BK=32 sub-steps
// per barrier (K=64/iter), ring-2 ping-pong of sub-step pairs, stage-at-top (8
// gload_lds) so 32 MFMAs + 16 ds_reads cover load latency before the vmcnt(0)
// drain (T3 minimum-2-phase). Barriers 32 -> 16. LDS 48 -> 64KB (2 blocks/CU;
// 768-block grid has a 256-block lone-tail phase — lone 4-wave blocks self-cover
// the drain with 128 wave-MFMAs/iter, unlike R14's asymmetric attn waves).
__global__ __launch_bounds__(256, 2) void gemm_qkv(
    const f16* __restrict__ A, const f16* __restrict__ B,
    f16* __restrict__ outq, f16* __restrict__ outk, f16* __restrict__ outvt)
{
    __shared__ f16 As[2][128 * 64];    // [buf][half*4096 + row*32 + u]
    __shared__ f16 Bs[2][128 * 64];
    const int tid = threadIdx.x;
    const int lane = tid & 63;
    const int wave = tid >> 6;
    const int wm = wave >> 1, wn = wave & 1;
    const int bm = blockIdx.y * 128, bn = blockIdx.x * 128;
    const int fr = lane & 15, fq = lane >> 4;

    const int srow = tid >> 2;                                    // 0..63
    const int su = (tid & 3) ^ (srow & 3) ^ ((srow >> 2) & 3);    // swizzled src 16B-unit
    const int uoff = (fq ^ (fr & 3) ^ ((fr >> 2) & 3)) * 8;       // lane-const read offset

    f32x4 acc[4][4] = {};

    // stage one 32-K step t into half hh of pair-buffer buf (4 gload_lds)
    auto stg32 = [&](int t, int buf, int hh) {
        const int k0 = t * 32;
        f16* Ad = &As[buf][hh * 4096];
        f16* Bd = &Bs[buf][hh * 4096];
        gload_lds16(&A[(bm + srow) * 1024 + k0 + su * 8],      &Ad[tid * 8]);
        gload_lds16(&A[(bm + 64 + srow) * 1024 + k0 + su * 8], &Ad[2048 + tid * 8]);
        gload_lds16(&B[(bn + srow) * 1024 + k0 + su * 8],      &Bd[tid * 8]);
        gload_lds16(&B[(bn + 64 + srow) * 1024 + k0 + su * 8], &Bd[2048 + tid * 8]);
    };

    // one 32-K compute half (16 MFMA), fragment addressing identical to R7
    auto half32 = [&](const f16* Asb, const f16* Bsb) {
        f16x8 af[4], bf[4];
#pragma unroll
        for (int mt = 0; mt < 4; ++mt)
            af[mt] = *(const f16x8*)&Asb[(wm * 64 + mt * 16 + fr) * 32 + uoff];
#pragma unroll
        for (int nt = 0; nt < 4; ++nt)
            bf[nt] = *(const f16x8*)&Bsb[(wn * 64 + nt * 16 + fr) * 32 + uoff];
        __builtin_amdgcn_s_setprio(1);
#pragma unroll
        for (int mt = 0; mt < 4; ++mt)
#pragma unroll
            for (int nt = 0; nt < 4; ++nt)
                acc[mt][nt] = MFMA16(af[mt], bf[nt], acc[mt][nt]);
        __builtin_amdgcn_s_setprio(0);
    };

    // prologue: stage pair 0 (steps 0,1), drain, barrier
    stg32(0, 0, 0);
    stg32(1, 0, 1);
    asm volatile("s_waitcnt vmcnt(0)" ::: "memory");
    __builtin_amdgcn_s_barrier();
    __builtin_amdgcn_sched_barrier(0);

#pragma unroll 1
    for (int ip = 0; ip < 16; ++ip) {       // 16 pair-iterations (K=64 each)
        const int buf = ip & 1;
        if (ip + 1 < 16) {                  // stage next pair before computing
            stg32(2 * ip + 2, buf ^ 1, 0);
            stg32(2 * ip + 3, buf ^ 1, 1);
        }
        half32(&As[buf][0],    &Bs[buf][0]);
        half32(&As[buf][4096], &Bs[buf][4096]);
        asm volatile("s_waitcnt vmcnt(0)" ::: "memory");
        __builtin_amdgcn_s_barrier();
        __builtin_amdgcn_sched_barrier(0);
    }

    const int x = blockIdx.x;
    if (x < 16) {
        // Q (x<8) or K block: uniform target, row-layout [bh][s][64]
        f16* base = (x < 8) ? outq : outk;
        const float scale = (x < 8) ? QSCALE : 1.0f;
        const int coloff = (x < 8) ? bn : (bn - 1024);
#pragma unroll
        for (int mt = 0; mt < 4; ++mt)
#pragma unroll
            for (int nt = 0; nt < 4; ++nt)
#pragma unroll
                for (int i = 0; i < 4; ++i) {
                    int row = bm + wm * 64 + mt * 16 + fq * 4 + i;  // (s*2+b)
                    int col = coloff + wn * 64 + nt * 16 + fr;      // 0..1023
                    int s = row >> 1, b = row & 1;
                    int h = col >> 6, dk = col & 63;
                    base[((b * 16 + h) * 2048 + s) * 64 + dk] = (f16)(acc[mt][nt][i] * scale);
                }
    } else {
        // V block: LDS transpose (2 passes over wn halves) -> vt[bh][dk][s]
        const int xb = x - 16;              // 0..7
        const int s0 = bm >> 1;             // 64-aligned s base
        f16* Ts = &As[0][0];                // [128][76] = 9728 f16 (fits in As[2][8192])
#pragma unroll
        for (int p = 0; p < 2; ++p) {
            __syncthreads();
            if (wn == p) {
#pragma unroll
                for (int mt = 0; mt < 4; ++mt)
#pragma unroll
                    for (int nt = 0; nt < 4; ++nt)
#pragma unroll
                        for (int i = 0; i < 4; ++i) {
                            int row = wm * 64 + mt * 16 + fq * 4 + i;  // 0..127 local
                            int cl = nt * 16 + fr;                     // 0..63 local col
                            Ts[(cl * 2 + (row & 1)) * 76 + (row >> 1)] = (f16)acc[mt][nt][i];
                        }
            }
            __syncthreads();
            const int h = xb * 2 + p;
            const int sj = tid & 7;
#pragma unroll
            for (int it = 0; it < 4; ++it) {
                int idx = (tid >> 3) + it * 32;     // 0..127
                int bsel = idx & 1, dk = idx >> 1;  // b, dk(=cl)
                f16x8 v = *(const f16x8*)&Ts[(dk * 2 + bsel) * 76 + sj * 8];
                *(f16x8*)&outvt[((bsel * 16 + h) * 64 + dk) * 2048 + s0 + sj * 8] = v;
            }
        }
    }
}

// ---------------- Flash attention (causal) — R17: KVBLK=128 pairs (kept) ----------------
__global__ __launch_bounds__(512) void attn_kernel(
    const f16* __restrict__ qg, const f16* __restrict__ kg,
    const f16* __restrict__ vtg, f16* __restrict__ attn)
{
    __shared__ f16 Ks[2][2 * 4096];
    __shared__ f16 Vs[2][2 * 4096];
    __shared__ f16 plds[8][16 * 64];
    const int tid = threadIdx.x;
    const int lane = tid & 63;
    const int wave = tid >> 6;      // 0..7

    // XCD-aware remap (bijective on 512): XCD = w&7 == bh&7
    const int w = blockIdx.x + (blockIdx.y << 4);
    const int xcd = w & 7;
    const int idx = w >> 3;                  // 0..63 within XCD, dispatch order
    const int bh = xcd + ((idx & 3) << 3);   // 0..31, bh%8 == xcd
    const int qpair = idx >> 2;              // 0..15, longest stream first

    const int b = bh >> 4, h = bh & 15;
    const int fr = lane & 15, fq = lane >> 4;

    const bool isB = wave < 4;
    const int w4 = wave & 3;
    const int qrow = (isB ? (31 - qpair) : qpair) * 64 + w4 * 16;  // wave's 16-row base
    const int nB = 32 - qpair;              // 64-chunks streamed by the block (>=17)
    const int nK = isB ? nB : (qpair + 1);  // 64-chunks this wave computes

    const f16* Q  = qg  + bh * 2048 * 64;
    const f16* K  = kg  + bh * 2048 * 64;
    const f16* VT = vtg + bh * 64 * 2048;
    f16* P = plds[wave];
    const int pswz = (fr & 7) << 3;         // XOR swizzle for P rows (f16 units)

    const int sr = tid >> 3;                // 0..63: full 64-row chunk in one issue
    const int scu = (tid & 7) ^ (sr & 7);

    f16x8 aq0 = *(const f16x8*)&Q[(qrow + fr) * 64 + fq * 8];
    f16x8 aq1 = *(const f16x8*)&Q[(qrow + fr) * 64 + 32 + fq * 8];

    f32x4 o[4] = {};
    float lsum = 0.f;

    // stage one 64-chunk (kc) into half h of pair-buffer buf
    auto stage64 = [&](int kc, int buf, int hh) {
        const int kb = kc * 64;
        gload_lds16(&K[(kb + sr) * 64 + scu * 8], &Ks[buf][hh * 4096 + tid * 8]);
        gload_lds16(&VT[sr * 2048 + kb + scu * 8], &Vs[buf][hh * 4096 + tid * 8]);
    };

    auto compute = [&](int kb, const f16* Ksb, const f16* Vsb, bool domask) {
        f32x4 sc[4] = {};
        // swapped QK^T: sc[ct][i] = S[k=kb+ct*16+fq*4+i][q=qrow+fr] (R8/R16-verified)
        __builtin_amdgcn_s_setprio(1);
#pragma unroll
        for (int ct = 0; ct < 4; ++ct) {
            int r = ct * 16 + fr;
            f16x8 kf0 = *(const f16x8*)&Ksb[r * 64 + ((fq ^ (r & 7)) * 8)];
            f16x8 kf1 = *(const f16x8*)&Ksb[r * 64 + (((4 + fq) ^ (r & 7)) * 8)];
            sc[ct] = MFMA16(kf0, aq0, sc[ct]);
            sc[ct] = MFMA16(kf1, aq1, sc[ct]);
        }
        __builtin_amdgcn_s_setprio(0);
        if (domask) {
#pragma unroll
            for (int ct = 0; ct < 4; ++ct) {
                int kk = kb + ct * 16 + fq * 4;   // k index of element i is kk+i
#pragma unroll
                for (int i = 0; i < 4; ++i)
                    if (kk + i > qrow + fr) sc[ct][i] = -1e30f;
            }
        }
        // exp2 + b64 P-spill into XOR-swizzled row: logical elem (16ct+4fq) -> ^pswz
#pragma unroll
        for (int ct = 0; ct < 4; ++ct) {
            float p0 = __builtin_amdgcn_exp2f(sc[ct][0]);
            float p1 = __builtin_amdgcn_exp2f(sc[ct][1]);
            float p2 = __builtin_amdgcn_exp2f(sc[ct][2]);
            float p3 = __builtin_amdgcn_exp2f(sc[ct][3]);
            lsum += (p0 + p1) + (p2 + p3);
            f16x4 pk = {(f16)p0, (f16)p1, (f16)p2, (f16)p3};
            *(f16x4*)&P[fr * 64 + ((ct * 16 + fq * 4) ^ pswz)] = pk;
        }
        // PV: ap = P[q=fr][k] (swizzle-consistent 8-elem reads)
        f16x8 ap0 = *(const f16x8*)&P[fr * 64 + ((fq * 8) ^ pswz)];
        f16x8 ap1 = *(const f16x8*)&P[fr * 64 + ((32 + fq * 8) ^ pswz)];
        __builtin_amdgcn_s_setprio(1);
#pragma unroll
        for (int nt = 0; nt < 4; ++nt) {
            int dk = nt * 16 + fr;
            f16x8 bv0 = *(const f16x8*)&Vsb[dk * 64 + ((fq ^ (dk & 7)) * 8)];
            f16x8 bv1 = *(const f16x8*)&Vsb[dk * 64 + (((4 + fq) ^ (dk & 7)) * 8)];
            o[nt] = MFMA16(ap0, bv0, o[nt]);
            o[nt] = MFMA16(ap1, bv1, o[nt]);
        }
        __builtin_amdgcn_s_setprio(0);
    };

    // prologue: stage pair 0 (chunks 0,1 — nB>=17 so both exist), drain, barrier
    stage64(0, 0, 0);
    stage64(1, 0, 1);
    asm volatile("s_waitcnt vmcnt(0)" ::: "memory");
    __builtin_amdgcn_s_barrier();
    __builtin_amdgcn_sched_barrier(0);

    const int nP = (nB + 1) >> 1;           // pair count (9..16)
#pragma unroll 1
    for (int ip = 0; ip < nP; ++ip) {
        const int buf = ip & 1;
        if (ip + 1 < nP) {
            stage64(2 * ip + 2, buf ^ 1, 0);
            if (2 * ip + 3 < nB) stage64(2 * ip + 3, buf ^ 1, 1);
        }
        const int kc0 = 2 * ip, kc1 = 2 * ip + 1;
        if (kc0 < nK) compute(kc0 * 64, &Ks[buf][0],    &Vs[buf][0],    kc0 * 64 + 63 > qrow);
        if (kc1 < nK) compute(kc1 * 64, &Ks[buf][4096], &Vs[buf][4096], kc1 * 64 + 63 > qrow);
        asm volatile("s_waitcnt vmcnt(0)" ::: "memory");
        __builtin_amdgcn_s_barrier();
        __builtin_amdgcn_sched_barrier(0);
    }

    // epilogue: lsum at lane (fr,fq) = partial row-sum for q=fr over its k-subset
    float rs = lsum;
    rs += __shfl_xor(rs, 16);
    rs += __shfl_xor(rs, 32);
    float inv = __builtin_amdgcn_rcpf(rs);
#pragma unroll
    for (int i = 0; i < 4; ++i) {
        float invi = __shfl(inv, fq * 4 + i);   // lane with fr == fq*4+i holds inv(q)
        int srow = qrow + fq * 4 + i;
#pragma unroll
        for (int nt = 0; nt < 4; ++nt)
            attn[(srow * 2 + b) * 1024 + h * 64 + nt * 16 + fr] = (f16)(o[nt][i] * invi);
    }
}

// ---------------- Out GEMM: out[4096x1024] = A[4096x1024] * Wout^T + bias ----------------
// R18: same pair-step transform (two BK=32 halves per barrier, ring-2). Grid 512 =
// exactly 2 blocks/CU -> no lone-tail phase. LDS 48KB. Barriers 32 -> 16.
__global__ __launch_bounds__(256) void gemm_out(
    const f16* __restrict__ A, const f16* __restrict__ B,
    const float* __restrict__ bias, float* __restrict__ out)
{
    __shared__ f16 As[2][128 * 64];    // [buf][half*4096 + row*32 + u]
    __shared__ f16 Bs[2][64 * 64];     // [buf][half*2048 + row*32 + u]
    const int tid = threadIdx.x;
    const int lane = tid & 63;
    const int wave = tid >> 6;
    const int wm = wave >> 1, wn = wave & 1;
    const int bm = blockIdx.y * 128, bn = blockIdx.x * 64;
    const int fr = lane & 15, fq = lane >> 4;

    const int srow = tid >> 2;                                    // 0..63
    const int su = (tid & 3) ^ (srow & 3) ^ ((srow >> 2) & 3);
    const int uoff = (fq ^ (fr & 3) ^ ((fr >> 2) & 3)) * 8;

    f32x4 acc[4][2] = {};

    auto stg32 = [&](int t, int buf, int hh) {
        const int k0 = t * 32;
        f16* Ad = &As[buf][hh * 4096];
        f16* Bd = &Bs[buf][hh * 2048];
        gload_lds16(&A[(bm + srow) * 1024 + k0 + su * 8],      &Ad[tid * 8]);
        gload_lds16(&A[(bm + 64 + srow) * 1024 + k0 + su * 8], &Ad[2048 + tid * 8]);
        gload_lds16(&B[(bn + srow) * 1024 + k0 + su * 8],      &Bd[tid * 8]);
    };

    auto half32 = [&](const f16* Asb, const f16* Bsb) {
        f16x8 af[4], bf[2];
#pragma unroll
        for (int mt = 0; mt < 4; ++mt)
            af[mt] = *(const f16x8*)&Asb[(wm * 64 + mt * 16 + fr) * 32 + uoff];
#pragma unroll
        for (int nt = 0; nt < 2; ++nt)
            bf[nt] = *(const f16x8*)&Bsb[(wn * 32 + nt * 16 + fr) * 32 + uoff];
        __builtin_amdgcn_s_setprio(1);
#pragma unroll
        for (int mt = 0; mt < 4; ++mt)
#pragma unroll
            for (int nt = 0; nt < 2; ++nt)
                acc[mt][nt] = MFMA16(af[mt], bf[nt], acc[mt][nt]);
        __builtin_amdgcn_s_setprio(0);
    };

    stg32(0, 0, 0);
    stg32(1, 0, 1);
    asm volatile("s_waitcnt vmcnt(0)" ::: "memory");
    __builtin_amdgcn_s_barrier();
    __builtin_amdgcn_sched_barrier(0);

#pragma unroll 1
    for (int ip = 0; ip < 16; ++ip) {
        const int buf = ip & 1;
        if (ip + 1 < 16) {
            stg32(2 * ip + 2, buf ^ 1, 0);
            stg32(2 * ip + 3, buf ^ 1, 1);
        }
        half32(&As[buf][0],    &Bs[buf][0]);
        half32(&As[buf][4096], &Bs[buf][2048]);
        asm volatile("s_waitcnt vmcnt(0)" ::: "memory");
        __builtin_amdgcn_s_barrier();
        __builtin_amdgcn_sched_barrier(0);
    }

#pragma unroll
    for (int mt = 0; mt < 4; ++mt)
#pragma unroll
        for (int nt = 0; nt < 2; ++nt)
#pragma unroll
            for (int i = 0; i < 4; ++i) {
                int row = bm + wm * 64 + mt * 16 + fq * 4 + i;
                int col = bn + wn * 32 + nt * 16 + fr;
                out[row * 1024 + col] = acc[mt][nt][i] + bias[col];
            }
}

extern "C" void kernel_launch(void* const* d_in, const int* in_sizes, int n_in,
                              void* d_out, int out_size, void* d_ws, size_t ws_size,
                              hipStream_t stream)
{
    const float* x     = (const float*)d_in[0];
    const float* w_qkv = (const float*)d_in[1];
    const float* w_out = (const float*)d_in[2];
    const float* b_out = (const float*)d_in[3];
    float* out = (float*)d_out;

    char* ws = (char*)d_ws;
    f16* xh  = (f16*)(ws);
    f16* wqh = (f16*)(ws + 8388608);
    f16* woh = (f16*)(ws + 14680064);
    f16* qh  = (f16*)(ws + 16777216);
    f16* kh  = (f16*)(ws + 25165824);
    f16* vt  = (f16*)(ws + 33554432);
    f16* ah  = (f16*)(ws + 41943040);

    cast_all<<<8192, 256, 0, stream>>>(x, w_qkv, w_out, xh);
    gemm_qkv<<<dim3(24, 32), 256, 0, stream>>>(xh, wqh, qh, kh, vt);
    attn_kernel<<<dim3(16, 32), 512, 0, stream>>>(qh, kh, vt, ah);
    gemm_out<<<dim3(16, 32), 256, 0, stream>>>(ah, woh, b_out, out);
}

// Round 14
// 165.249 us; speedup vs baseline: 1.0429x; 1.0429x over previous
//
#include <hip/hip_runtime.h>
#include <cstdint>

typedef _Float16 f16;
typedef _Float16 f16x4 __attribute__((ext_vector_type(4)));
typedef _Float16 f16x8 __attribute__((ext_vector_type(8)));
typedef float f32x4 __attribute__((ext_vector_type(4)));

#define MFMA16(a, b, c) __builtin_amdgcn_mfma_f32_16x16x32_f16(a, b, c, 0, 0, 0)
#define QSCALE 0.1803368801111243f  /* 0.125 * log2(e): scores land in log2 domain */

// direct global->LDS 16B async copy (m97 pattern)
__device__ __forceinline__ void gload_lds16(const void* g, void* l) {
    __builtin_amdgcn_global_load_lds((__attribute__((address_space(1))) void*)(g),
                                     (__attribute__((address_space(3))) void*)(l),
                                     16, 0, 0);
}

// Problem constants: S=2048, B=2, D=1024, H=16, DK=64
// ws layout (bytes):
//  xh   @ 0         : 4096x1024 f16 = 8 MB       (dead after gemm_qkv)
//  wqh  @ 8388608   : 3072x1024 f16 = 6 MB
//  woh  @ 14680064  : 1024x1024 f16 = 2 MB
//  qh   @ 16777216  : [32][2048][64] f16 = 8 MB  (PRE-SCALED by 0.125*log2e)
//  kh   @ 25165824  : [32][2048][64] f16 = 8 MB
//  vt   @ 33554432  : [32][64][2048] f16 = 8 MB  (V transposed, written by gemm_qkv)
//  ah   @ 41943040  : [4096][1024] f16 = 8 MB

// Single fused cast: outputs are contiguous in ws (xh | wqh | woh).
__global__ void cast_all(const float* __restrict__ x, const float* __restrict__ wqv,
                         const float* __restrict__ wo, f16* __restrict__ out) {
    int i = blockIdx.x * blockDim.x + threadIdx.x;  // 0..2097151 float4s
    const float* src; int li;
    if (i < 1048576)      { src = x;   li = i; }
    else if (i < 1835008) { src = wqv; li = i - 1048576; }
    else                  { src = wo;  li = i - 1835008; }
    float4 v = reinterpret_cast<const float4*>(src)[li];
    f16x4 o = {(f16)v.x, (f16)v.y, (f16)v.z, (f16)v.w};
    reinterpret_cast<f16x4*>(out)[i] = o;
}

// ---------------- QKV GEMM: C[4096x3072] = X[4096x1024] * Wqkv^T ----------------
// R19: REVERT to R7 ring-3 BK=32 structure (R18's pair-step hit its pre-committed
// failure signature: bank conflicts 65K->3.2M, 2 blocks/CU + lone tail).
// NEW: XCD-aware 2D-chunked remap (T1, attn precedent R10: FETCH 62->12MB).
// Old spray: each XCD touches ~14MB of A+B (FETCH 40MB = 2.9x ideal). New: each
// XCD owns a 12x8 block region -> working set 3MB B + 2MB A = 5MB ~ L2.
// Bijective: 24 x-panels = 2x12, 32 y-panels = 4x8; XCD = (w&7) = rx + 2*ry.
__global__ __launch_bounds__(256, 3) void gemm_qkv(
    const f16* __restrict__ A, const f16* __restrict__ B,
    f16* __restrict__ outq, f16* __restrict__ outk, f16* __restrict__ outvt)
{
    __shared__ f16 As[3][128 * 32];
    __shared__ f16 Bs[3][128 * 32];
    const int tid = threadIdx.x;
    const int lane = tid & 63;
    const int wave = tid >> 6;
    const int wm = wave >> 1, wn = wave & 1;

    // XCD-aware 2D-chunked remap: HW linear id -> (bxx, byy) region per XCD
    const int wlin = blockIdx.x + 24 * blockIdx.y;
    const int xcd = wlin & 7;
    const int ii = wlin >> 3;                    // 0..95 within XCD
    const int bxx = 12 * (xcd & 1) + (ii % 12);  // 0..23
    const int byy = 8 * (xcd >> 1) + (ii / 12);  // 0..31

    const int bm = byy * 128, bn = bxx * 128;
    const int fr = lane & 15, fq = lane >> 4;

    const int srow = tid >> 2;                                    // 0..63
    const int su = (tid & 3) ^ (srow & 3) ^ ((srow >> 2) & 3);    // swizzled src 16B-unit
    const int uoff = (fq ^ (fr & 3) ^ ((fr >> 2) & 3)) * 8;       // lane-const read offset

    f32x4 acc[4][4] = {};

    auto stg = [&](int tt, int buf) {
        const int k0 = tt * 32;
        gload_lds16(&A[(bm + srow) * 1024 + k0 + su * 8],      &As[buf][tid * 8]);
        gload_lds16(&A[(bm + 64 + srow) * 1024 + k0 + su * 8], &As[buf][2048 + tid * 8]);
        gload_lds16(&B[(bn + srow) * 1024 + k0 + su * 8],      &Bs[buf][tid * 8]);
        gload_lds16(&B[(bn + 64 + srow) * 1024 + k0 + su * 8], &Bs[buf][2048 + tid * 8]);
    };

    auto step = [&](int t, int buf) {
        const int b2 = (buf + 2 >= 3) ? (buf - 1) : (buf + 2);
        if (t < 30) stg(t + 2, b2);
        f16x8 af[4], bf[4];
#pragma unroll
        for (int mt = 0; mt < 4; ++mt)
            af[mt] = *(const f16x8*)&As[buf][(wm * 64 + mt * 16 + fr) * 32 + uoff];
#pragma unroll
        for (int nt = 0; nt < 4; ++nt)
            bf[nt] = *(const f16x8*)&Bs[buf][(wn * 64 + nt * 16 + fr) * 32 + uoff];
        __builtin_amdgcn_s_setprio(1);
#pragma unroll
        for (int mt = 0; mt < 4; ++mt)
#pragma unroll
            for (int nt = 0; nt < 4; ++nt)
                acc[mt][nt] = MFMA16(af[mt], bf[nt], acc[mt][nt]);
        __builtin_amdgcn_s_setprio(0);
        if (t < 30) { asm volatile("s_waitcnt vmcnt(4)" ::: "memory"); }
        else        { asm volatile("s_waitcnt vmcnt(0)" ::: "memory"); }
        __builtin_amdgcn_s_barrier();
        __builtin_amdgcn_sched_barrier(0);
    };

    stg(0, 0);
    stg(1, 1);
    asm volatile("s_waitcnt vmcnt(4)" ::: "memory");
    __builtin_amdgcn_s_barrier();
    __builtin_amdgcn_sched_barrier(0);
#pragma unroll 1
    for (int tb = 0; tb < 30; tb += 3) {
        step(tb, 0);
        step(tb + 1, 1);
        step(tb + 2, 2);
    }
    step(30, 0);
    step(31, 1);

    const int x = bxx;
    if (x < 16) {
        // Q (x<8) or K block: uniform target, row-layout [bh][s][64]
        f16* base = (x < 8) ? outq : outk;
        const float scale = (x < 8) ? QSCALE : 1.0f;
        const int coloff = (x < 8) ? bn : (bn - 1024);
#pragma unroll
        for (int mt = 0; mt < 4; ++mt)
#pragma unroll
            for (int nt = 0; nt < 4; ++nt)
#pragma unroll
                for (int i = 0; i < 4; ++i) {
                    int row = bm + wm * 64 + mt * 16 + fq * 4 + i;  // (s*2+b)
                    int col = coloff + wn * 64 + nt * 16 + fr;      // 0..1023
                    int s = row >> 1, b = row & 1;
                    int h = col >> 6, dk = col & 63;
                    base[((b * 16 + h) * 2048 + s) * 64 + dk] = (f16)(acc[mt][nt][i] * scale);
                }
    } else {
        // V block: LDS transpose (2 passes over wn halves) -> vt[bh][dk][s]
        const int xb = x - 16;              // 0..7
        const int s0 = bm >> 1;             // 64-aligned s base
        f16* Ts = &As[0][0];                // [128][76] = 9728 f16 (fits in As[3][4096])
#pragma unroll
        for (int p = 0; p < 2; ++p) {
            __syncthreads();
            if (wn == p) {
#pragma unroll
                for (int mt = 0; mt < 4; ++mt)
#pragma unroll
                    for (int nt = 0; nt < 4; ++nt)
#pragma unroll
                        for (int i = 0; i < 4; ++i) {
                            int row = wm * 64 + mt * 16 + fq * 4 + i;  // 0..127 local
                            int cl = nt * 16 + fr;                     // 0..63 local col
                            Ts[(cl * 2 + (row & 1)) * 76 + (row >> 1)] = (f16)acc[mt][nt][i];
                        }
            }
            __syncthreads();
            const int h = xb * 2 + p;
            const int sj = tid & 7;
#pragma unroll
            for (int it = 0; it < 4; ++it) {
                int idx = (tid >> 3) + it * 32;     // 0..127
                int bsel = idx & 1, dk = idx >> 1;  // b, dk(=cl)
                f16x8 v = *(const f16x8*)&Ts[(dk * 2 + bsel) * 76 + sj * 8];
                *(f16x8*)&outvt[((bsel * 16 + h) * 64 + dk) * 2048 + s0 + sj * 8] = v;
            }
        }
    }
}

// ---------------- Flash attention (causal) — R17: KVBLK=128 pairs (kept, best) ----------
__global__ __launch_bounds__(512) void attn_kernel(
    const f16* __restrict__ qg, const f16* __restrict__ kg,
    const f16* __restrict__ vtg, f16* __restrict__ attn)
{
    __shared__ f16 Ks[2][2 * 4096];
    __shared__ f16 Vs[2][2 * 4096];
    __shared__ f16 plds[8][16 * 64];
    const int tid = threadIdx.x;
    const int lane = tid & 63;
    const int wave = tid >> 6;      // 0..7

    // XCD-aware remap (bijective on 512): XCD = w&7 == bh&7
    const int w = blockIdx.x + (blockIdx.y << 4);
    const int xcd = w & 7;
    const int idx = w >> 3;                  // 0..63 within XCD, dispatch order
    const int bh = xcd + ((idx & 3) << 3);   // 0..31, bh%8 == xcd
    const int qpair = idx >> 2;              // 0..15, longest stream first

    const int b = bh >> 4, h = bh & 15;
    const int fr = lane & 15, fq = lane >> 4;

    const bool isB = wave < 4;
    const int w4 = wave & 3;
    const int qrow = (isB ? (31 - qpair) : qpair) * 64 + w4 * 16;  // wave's 16-row base
    const int nB = 32 - qpair;              // 64-chunks streamed by the block (>=17)
    const int nK = isB ? nB : (qpair + 1);  // 64-chunks this wave computes

    const f16* Q  = qg  + bh * 2048 * 64;
    const f16* K  = kg  + bh * 2048 * 64;
    const f16* VT = vtg + bh * 64 * 2048;
    f16* P = plds[wave];
    const int pswz = (fr & 7) << 3;         // XOR swizzle for P rows (f16 units)

    const int sr = tid >> 3;                // 0..63: full 64-row chunk in one issue
    const int scu = (tid & 7) ^ (sr & 7);

    f16x8 aq0 = *(const f16x8*)&Q[(qrow + fr) * 64 + fq * 8];
    f16x8 aq1 = *(const f16x8*)&Q[(qrow + fr) * 64 + 32 + fq * 8];

    f32x4 o[4] = {};
    float lsum = 0.f;

    // stage one 64-chunk (kc) into half h of pair-buffer buf
    auto stage64 = [&](int kc, int buf, int hh) {
        const int kb = kc * 64;
        gload_lds16(&K[(kb + sr) * 64 + scu * 8], &Ks[buf][hh * 4096 + tid * 8]);
        gload_lds16(&VT[sr * 2048 + kb + scu * 8], &Vs[buf][hh * 4096 + tid * 8]);
    };

    auto compute = [&](int kb, const f16* Ksb, const f16* Vsb, bool domask) {
        f32x4 sc[4] = {};
        // swapped QK^T: sc[ct][i] = S[k=kb+ct*16+fq*4+i][q=qrow+fr] (R8/R16-verified)
        __builtin_amdgcn_s_setprio(1);
#pragma unroll
        for (int ct = 0; ct < 4; ++ct) {
            int r = ct * 16 + fr;
            f16x8 kf0 = *(const f16x8*)&Ksb[r * 64 + ((fq ^ (r & 7)) * 8)];
            f16x8 kf1 = *(const f16x8*)&Ksb[r * 64 + (((4 + fq) ^ (r & 7)) * 8)];
            sc[ct] = MFMA16(kf0, aq0, sc[ct]);
            sc[ct] = MFMA16(kf1, aq1, sc[ct]);
        }
        __builtin_amdgcn_s_setprio(0);
        if (domask) {
#pragma unroll
            for (int ct = 0; ct < 4; ++ct) {
                int kk = kb + ct * 16 + fq * 4;   // k index of element i is kk+i
#pragma unroll
                for (int i = 0; i < 4; ++i)
                    if (kk + i > qrow + fr) sc[ct][i] = -1e30f;
            }
        }
        // exp2 + b64 P-spill into XOR-swizzled row: logical elem (16ct+4fq) -> ^pswz
#pragma unroll
        for (int ct = 0; ct < 4; ++ct) {
            float p0 = __builtin_amdgcn_exp2f(sc[ct][0]);
            float p1 = __builtin_amdgcn_exp2f(sc[ct][1]);
            float p2 = __builtin_amdgcn_exp2f(sc[ct][2]);
            float p3 = __builtin_amdgcn_exp2f(sc[ct][3]);
            lsum += (p0 + p1) + (p2 + p3);
            f16x4 pk = {(f16)p0, (f16)p1, (f16)p2, (f16)p3};
            *(f16x4*)&P[fr * 64 + ((ct * 16 + fq * 4) ^ pswz)] = pk;
        }
        // PV: ap = P[q=fr][k] (swizzle-consistent 8-elem reads)
        f16x8 ap0 = *(const f16x8*)&P[fr * 64 + ((fq * 8) ^ pswz)];
        f16x8 ap1 = *(const f16x8*)&P[fr * 64 + ((32 + fq * 8) ^ pswz)];
        __builtin_amdgcn_s_setprio(1);
#pragma unroll
        for (int nt = 0; nt < 4; ++nt) {
            int dk = nt * 16 + fr;
            f16x8 bv0 = *(const f16x8*)&Vsb[dk * 64 + ((fq ^ (dk & 7)) * 8)];
            f16x8 bv1 = *(const f16x8*)&Vsb[dk * 64 + (((4 + fq) ^ (dk & 7)) * 8)];
            o[nt] = MFMA16(ap0, bv0, o[nt]);
            o[nt] = MFMA16(ap1, bv1, o[nt]);
        }
        __builtin_amdgcn_s_setprio(0);
    };

    // prologue: stage pair 0 (chunks 0,1 — nB>=17 so both exist), drain, barrier
    stage64(0, 0, 0);
    stage64(1, 0, 1);
    asm volatile("s_waitcnt vmcnt(0)" ::: "memory");
    __builtin_amdgcn_s_barrier();
    __builtin_amdgcn_sched_barrier(0);

    const int nP = (nB + 1) >> 1;           // pair count (9..16)
#pragma unroll 1
    for (int ip = 0; ip < nP; ++ip) {
        const int buf = ip & 1;
        if (ip + 1 < nP) {
            stage64(2 * ip + 2, buf ^ 1, 0);
            if (2 * ip + 3 < nB) stage64(2 * ip + 3, buf ^ 1, 1);
        }
        const int kc0 = 2 * ip, kc1 = 2 * ip + 1;
        if (kc0 < nK) compute(kc0 * 64, &Ks[buf][0],    &Vs[buf][0],    kc0 * 64 + 63 > qrow);
        if (kc1 < nK) compute(kc1 * 64, &Ks[buf][4096], &Vs[buf][4096], kc1 * 64 + 63 > qrow);
        asm volatile("s_waitcnt vmcnt(0)" ::: "memory");
        __builtin_amdgcn_s_barrier();
        __builtin_amdgcn_sched_barrier(0);
    }

    // epilogue: lsum at lane (fr,fq) = partial row-sum for q=fr over its k-subset
    float rs = lsum;
    rs += __shfl_xor(rs, 16);
    rs += __shfl_xor(rs, 32);
    float inv = __builtin_amdgcn_rcpf(rs);
#pragma unroll
    for (int i = 0; i < 4; ++i) {
        float invi = __shfl(inv, fq * 4 + i);   // lane with fr == fq*4+i holds inv(q)
        int srow = qrow + fq * 4 + i;
#pragma unroll
        for (int nt = 0; nt < 4; ++nt)
            attn[(srow * 2 + b) * 1024 + h * 64 + nt * 16 + fr] = (f16)(o[nt][i] * invi);
    }
}

// ---------------- Out GEMM: out[4096x1024] = A[4096x1024] * Wout^T + bias ----------------
// R19: revert to R7 ring-3 BK=32 structure + XCD-aware 2D-chunked remap
// (8x8 region per XCD: 1MB B + 2MB A = 3MB < 4MB L2). Bijective: 16=2x8, 32=4x8.
__global__ __launch_bounds__(256) void gemm_out(
    const f16* __restrict__ A, const f16* __restrict__ B,
    const float* __restrict__ bias, float* __restrict__ out)
{
    __shared__ f16 As[3][128 * 32];
    __shared__ f16 Bs[3][64 * 32];
    const int tid = threadIdx.x;
    const int lane = tid & 63;
    const int wave = tid >> 6;
    const int wm = wave >> 1, wn = wave & 1;

    const int wlin = blockIdx.x + 16 * blockIdx.y;
    const int xcd = wlin & 7;
    const int ii = wlin >> 3;                   // 0..63
    const int bxx = 8 * (xcd & 1) + (ii & 7);   // 0..15
    const int byy = 8 * (xcd >> 1) + (ii >> 3); // 0..31

    const int bm = byy * 128, bn = bxx * 64;
    const int fr = lane & 15, fq = lane >> 4;

    const int srow = tid >> 2;                                    // 0..63
    const int su = (tid & 3) ^ (srow & 3) ^ ((srow >> 2) & 3);
    const int uoff = (fq ^ (fr & 3) ^ ((fr >> 2) & 3)) * 8;

    f32x4 acc[4][2] = {};

    auto stg = [&](int tt, int buf) {
        const int k0 = tt * 32;
        gload_lds16(&A[(bm + srow) * 1024 + k0 + su * 8],      &As[buf][tid * 8]);
        gload_lds16(&A[(bm + 64 + srow) * 1024 + k0 + su * 8], &As[buf][2048 + tid * 8]);
        gload_lds16(&B[(bn + srow) * 1024 + k0 + su * 8],      &Bs[buf][tid * 8]);
    };

    auto step = [&](int t, int buf) {
        const int b2 = (buf + 2 >= 3) ? (buf - 1) : (buf + 2);
        if (t < 30) stg(t + 2, b2);
        f16x8 af[4], bf[2];
#pragma unroll
        for (int mt = 0; mt < 4; ++mt)
            af[mt] = *(const f16x8*)&As[buf][(wm * 64 + mt * 16 + fr) * 32 + uoff];
#pragma unroll
        for (int nt = 0; nt < 2; ++nt)
            bf[nt] = *(const f16x8*)&Bs[buf][(wn * 32 + nt * 16 + fr) * 32 + uoff];
        __builtin_amdgcn_s_setprio(1);
#pragma unroll
        for (int mt = 0; mt < 4; ++mt)
#pragma unroll
            for (int nt = 0; nt < 2; ++nt)
                acc[mt][nt] = MFMA16(af[mt], bf[nt], acc[mt][nt]);
        __builtin_amdgcn_s_setprio(0);
        if (t < 30) { asm volatile("s_waitcnt vmcnt(3)" ::: "memory"); }
        else        { asm volatile("s_waitcnt vmcnt(0)" ::: "memory"); }
        __builtin_amdgcn_s_barrier();
        __builtin_amdgcn_sched_barrier(0);
    };

    stg(0, 0);
    stg(1, 1);
    asm volatile("s_waitcnt vmcnt(3)" ::: "memory");
    __builtin_amdgcn_s_barrier();
    __builtin_amdgcn_sched_barrier(0);
#pragma unroll 1
    for (int tb = 0; tb < 30; tb += 3) {
        step(tb, 0);
        step(tb + 1, 1);
        step(tb + 2, 2);
    }
    step(30, 0);
    step(31, 1);

#pragma unroll
    for (int mt = 0; mt < 4; ++mt)
#pragma unroll
        for (int nt = 0; nt < 2; ++nt)
#pragma unroll
            for (int i = 0; i < 4; ++i) {
                int row = bm + wm * 64 + mt * 16 + fq * 4 + i;
                int col = bn + wn * 32 + nt * 16 + fr;
                out[row * 1024 + col] = acc[mt][nt][i] + bias[col];
            }
}

extern "C" void kernel_launch(void* const* d_in, const int* in_sizes, int n_in,
                              void* d_out, int out_size, void* d_ws, size_t ws_size,
                              hipStream_t stream)
{
    const float* x     = (const float*)d_in[0];
    const float* w_qkv = (const float*)d_in[1];
    const float* w_out = (const float*)d_in[2];
    const float* b_out = (const float*)d_in[3];
    float* out = (float*)d_out;

    char* ws = (char*)d_ws;
    f16* xh  = (f16*)(ws);
    f16* wqh = (f16*)(ws + 8388608);
    f16* woh = (f16*)(ws + 14680064);
    f16* qh  = (f16*)(ws + 16777216);
    f16* kh  = (f16*)(ws + 25165824);
    f16* vt  = (f16*)(ws + 33554432);
    f16* ah  = (f16*)(ws + 41943040);

    cast_all<<<8192, 256, 0, stream>>>(x, w_qkv, w_out, xh);
    gemm_qkv<<<dim3(24, 32), 256, 0, stream>>>(xh, wqh, qh, kh, vt);
    attn_kernel<<<dim3(16, 32), 512, 0, stream>>>(qh, kh, vt, ah);
    gemm_out<<<dim3(16, 32), 256, 0, stream>>>(ah, woh, b_out, out);
}